// Round 1
// baseline (423.052 us; speedup 1.0000x reference)
//
#include <hip/hip_runtime.h>

#define BATCH 4096
#define ISZ   1024
#define HSZ   2048

typedef __bf16 bf16x8 __attribute__((ext_vector_type(8)));
typedef float  f32x4  __attribute__((ext_vector_type(4)));

// ---------- fp32 -> bf16 (RNE) ----------
__device__ __forceinline__ unsigned short f2bf(float f) {
  unsigned u = __builtin_bit_cast(unsigned, f);
  u += 0x7fffu + ((u >> 16) & 1u);
  return (unsigned short)(u >> 16);
}

__global__ __launch_bounds__(256) void cvt_bf16_kernel(const float* __restrict__ src,
                                                       unsigned short* __restrict__ dst,
                                                       int n4) {
  int i = blockIdx.x * 256 + threadIdx.x;
  if (i >= n4) return;
  float4 f = ((const float4*)src)[i];
  ushort4 o;
  o.x = f2bf(f.x); o.y = f2bf(f.y); o.z = f2bf(f.z); o.w = f2bf(f.w);
  ((ushort4*)dst)[i] = o;
}

// ---------- GEMM core (m97 structure) ----------
// Tile in LDS: 128 rows x 32 k, bf16 row-major, 64 B/row, 8192 B total.
// Staged with global_load_lds width=16: thread t covers tile bytes
// {t*16, t*16+4096}; LDS dest must be wave-uniform base + lane*16.
__device__ __forceinline__ void stage_tile(const unsigned short* __restrict__ g, int ldK,
                                           int tileRow, int k0, char* lds, int t) {
  int r  = t >> 2;                 // 0..63  (row within first 64-row half)
  int ke = (t & 3) * 8;            // k element offset (8 bf16 = 16 B)
  const unsigned short* g0 = g + (tileRow + r) * ldK + (k0 + ke);
  const unsigned short* g1 = g0 + 64 * ldK;
  char* l0 = lds + ((t >> 6) << 10);   // wave-uniform base: wid*1024
  __builtin_amdgcn_global_load_lds((const __attribute__((address_space(1))) void*)g0,
                                   (__attribute__((address_space(3))) void*)l0, 16, 0, 0);
  __builtin_amdgcn_global_load_lds((const __attribute__((address_space(1))) void*)g1,
                                   (__attribute__((address_space(3))) void*)(l0 + 4096), 16, 0, 0);
}

// C[row, col] += A[rowBase..+128, 0..K) * W[colBase..+128, 0..K)^T
// A, W both row-major with K contiguous (exactly the "B^T input" layout).
__device__ __forceinline__ void gemm_seg(const unsigned short* __restrict__ A,
                                         const unsigned short* __restrict__ W,
                                         int K, int rowBase, int colBase,
                                         char* ldsA, char* ldsB,
                                         f32x4 (&acc)[4][4], int t) {
  const int lane = t & 63;
  const int wid  = t >> 6;
  const int wm   = wid >> 1, wn = wid & 1;   // wave 2x2 -> 64x64 each
  const int lrow = lane & 15;
  const int quad = lane >> 4;
  for (int k0 = 0; k0 < K; k0 += 32) {
    stage_tile(A, K, rowBase, k0, ldsA, t);
    stage_tile(W, K, colBase, k0, ldsB, t);
    __syncthreads();                          // drains vmcnt -> LDS ready
    bf16x8 af[4], bfr[4];
#pragma unroll
    for (int i = 0; i < 4; ++i) {
      af[i]  = *(const bf16x8*)(ldsA + (wm * 64 + i * 16 + lrow) * 64 + quad * 16);
      bfr[i] = *(const bf16x8*)(ldsB + (wn * 64 + i * 16 + lrow) * 64 + quad * 16);
    }
#pragma unroll
    for (int i = 0; i < 4; ++i)
#pragma unroll
      for (int j = 0; j < 4; ++j)
        acc[i][j] = __builtin_amdgcn_mfma_f32_16x16x32_bf16(af[i], bfr[j], acc[i][j], 0, 0, 0);
    __syncthreads();                          // all reads done before restage
  }
}

__device__ __forceinline__ float fast_sigmoid(float v) {
  return 1.0f / (1.0f + __expf(-v));
}
__device__ __forceinline__ float fast_tanh(float v) {
  float e = __expf(2.0f * v);
  return 1.0f - 2.0f / (e + 1.0f);   // safe at +/-inf
}

// ---------- Kernel A: R and Z gates (blockIdx.z: 0 -> R, 1 -> Z) ----------
__global__ __launch_bounds__(256) void gate_rz(
    const unsigned short* __restrict__ xb, const unsigned short* __restrict__ hb,
    const unsigned short* __restrict__ Wr, const unsigned short* __restrict__ Ur,
    const unsigned short* __restrict__ Wz, const unsigned short* __restrict__ Uz,
    const float* __restrict__ br, const float* __restrict__ bz,
    const float* __restrict__ hprev,
    unsigned short* __restrict__ rh, float* __restrict__ Zbuf) {
  __shared__ char lds[16384];
  char* ldsA = lds;
  char* ldsB = lds + 8192;
  const int t = threadIdx.x;
  const int rowBase = blockIdx.y * 128;
  const int colBase = blockIdx.x * 128;
  const bool isZ = (blockIdx.z != 0);
  const unsigned short* W = isZ ? Wz : Wr;
  const unsigned short* U = isZ ? Uz : Ur;
  const float* bias = isZ ? bz : br;

  f32x4 acc[4][4];
#pragma unroll
  for (int i = 0; i < 4; ++i)
#pragma unroll
    for (int j = 0; j < 4; ++j)
      acc[i][j] = (f32x4){0.f, 0.f, 0.f, 0.f};

  gemm_seg(xb, W, ISZ, rowBase, colBase, ldsA, ldsB, acc, t);
  gemm_seg(hb, U, HSZ, rowBase, colBase, ldsA, ldsB, acc, t);

  const int lane = t & 63, wid = t >> 6;
  const int wm = wid >> 1, wn = wid & 1, lrow = lane & 15, quad = lane >> 4;
#pragma unroll
  for (int i = 0; i < 4; ++i) {
#pragma unroll
    for (int j = 0; j < 4; ++j) {
      int col = colBase + wn * 64 + j * 16 + lrow;
      float bv = bias[col];
#pragma unroll
      for (int r = 0; r < 4; ++r) {
        int row = rowBase + wm * 64 + i * 16 + quad * 4 + r;
        float s = fast_sigmoid(acc[i][j][r] + bv);
        int idx = row * HSZ + col;
        if (isZ) {
          Zbuf[idx] = s;
        } else {
          rh[idx] = f2bf(s * hprev[idx]);
        }
      }
    }
  }
}

// ---------- Kernel B: candidate h + final blend ----------
__global__ __launch_bounds__(256) void gate_h(
    const unsigned short* __restrict__ xb, const unsigned short* __restrict__ rhb,
    const unsigned short* __restrict__ Wh, const unsigned short* __restrict__ Uh,
    const float* __restrict__ bh, const float* __restrict__ Zbuf,
    const float* __restrict__ hprev, float* __restrict__ out) {
  __shared__ char lds[16384];
  char* ldsA = lds;
  char* ldsB = lds + 8192;
  const int t = threadIdx.x;
  const int rowBase = blockIdx.y * 128;
  const int colBase = blockIdx.x * 128;

  f32x4 acc[4][4];
#pragma unroll
  for (int i = 0; i < 4; ++i)
#pragma unroll
    for (int j = 0; j < 4; ++j)
      acc[i][j] = (f32x4){0.f, 0.f, 0.f, 0.f};

  gemm_seg(xb, Wh, ISZ, rowBase, colBase, ldsA, ldsB, acc, t);
  gemm_seg(rhb, Uh, HSZ, rowBase, colBase, ldsA, ldsB, acc, t);

  const int lane = t & 63, wid = t >> 6;
  const int wm = wid >> 1, wn = wid & 1, lrow = lane & 15, quad = lane >> 4;
#pragma unroll
  for (int i = 0; i < 4; ++i) {
#pragma unroll
    for (int j = 0; j < 4; ++j) {
      int col = colBase + wn * 64 + j * 16 + lrow;
      float bv = bh[col];
#pragma unroll
      for (int r = 0; r < 4; ++r) {
        int row = rowBase + wm * 64 + i * 16 + quad * 4 + r;
        float hp = fast_tanh(acc[i][j][r] + bv);
        int idx = row * HSZ + col;
        float z = Zbuf[idx];
        float h = hprev[idx];
        out[idx] = h + z * (hp - h);
      }
    }
  }
}

// ---------- host ----------
extern "C" void kernel_launch(void* const* d_in, const int* in_sizes, int n_in,
                              void* d_out, int out_size, void* d_ws, size_t ws_size,
                              hipStream_t stream) {
  (void)in_sizes; (void)n_in; (void)out_size; (void)ws_size;
  const float* x     = (const float*)d_in[0];
  const float* hprev = (const float*)d_in[1];
  const float* Wh    = (const float*)d_in[2];
  const float* Wz    = (const float*)d_in[3];
  const float* Wr    = (const float*)d_in[4];
  const float* Uh    = (const float*)d_in[5];
  const float* Uz    = (const float*)d_in[6];
  const float* Ur    = (const float*)d_in[7];
  const float* bh    = (const float*)d_in[8];
  const float* bz    = (const float*)d_in[9];
  const float* br    = (const float*)d_in[10];
  float* out = (float*)d_out;

  char* ws = (char*)d_ws;
  size_t off = 0;
  auto alloc = [&](size_t bytes) { char* p = ws + off; off += bytes; return p; };
  unsigned short* xb  = (unsigned short*)alloc((size_t)BATCH * ISZ * 2);  // 8 MB
  unsigned short* hb  = (unsigned short*)alloc((size_t)BATCH * HSZ * 2);  // 16 MB
  unsigned short* Wrb = (unsigned short*)alloc((size_t)HSZ * ISZ * 2);    // 4 MB
  unsigned short* Wzb = (unsigned short*)alloc((size_t)HSZ * ISZ * 2);    // 4 MB
  unsigned short* Whb = (unsigned short*)alloc((size_t)HSZ * ISZ * 2);    // 4 MB
  unsigned short* Urb = (unsigned short*)alloc((size_t)HSZ * HSZ * 2);    // 8 MB
  unsigned short* Uzb = (unsigned short*)alloc((size_t)HSZ * HSZ * 2);    // 8 MB
  unsigned short* Uhb = (unsigned short*)alloc((size_t)HSZ * HSZ * 2);    // 8 MB
  unsigned short* rhb = (unsigned short*)alloc((size_t)BATCH * HSZ * 2);  // 16 MB
  float*          Zb  = (float*)alloc((size_t)BATCH * HSZ * 4);           // 32 MB
  // total 108 MB of ws

  auto cvt = [&](const float* s, unsigned short* d, int n) {
    int n4 = n / 4;
    cvt_bf16_kernel<<<(n4 + 255) / 256, 256, 0, stream>>>(s, d, n4);
  };
  cvt(x,     xb,  BATCH * ISZ);
  cvt(hprev, hb,  BATCH * HSZ);
  cvt(Wr,    Wrb, HSZ * ISZ);
  cvt(Wz,    Wzb, HSZ * ISZ);
  cvt(Wh,    Whb, HSZ * ISZ);
  cvt(Ur,    Urb, HSZ * HSZ);
  cvt(Uz,    Uzb, HSZ * HSZ);
  cvt(Uh,    Uhb, HSZ * HSZ);

  dim3 gridA(HSZ / 128, BATCH / 128, 2);
  gate_rz<<<gridA, 256, 0, stream>>>(xb, hb, Wrb, Urb, Wzb, Uzb, br, bz, hprev, rhb, Zb);

  dim3 gridB(HSZ / 128, BATCH / 128, 1);
  gate_h<<<gridB, 256, 0, stream>>>(xb, rhb, Whb, Uhb, bh, Zb, hprev, out);
}

// Round 2
// 379.687 us; speedup vs baseline: 1.1142x; 1.1142x over previous
//
#include <hip/hip_runtime.h>

#define BATCH 4096
#define ISZ   1024
#define HSZ   2048

typedef __bf16 bf16x8 __attribute__((ext_vector_type(8)));
typedef float  f32x4  __attribute__((ext_vector_type(4)));

// ---------- fp32 -> bf16 (RNE) ----------
__device__ __forceinline__ unsigned short f2bf(float f) {
  unsigned u = __builtin_bit_cast(unsigned, f);
  u += 0x7fffu + ((u >> 16) & 1u);
  return (unsigned short)(u >> 16);
}

// ---------- fused convert: all 8 tensors in ONE launch ----------
struct CvtArgs {
  const float* src[8];
  unsigned short* dst[8];
  int cum[9];   // prefix sums of float4 counts
};

__global__ __launch_bounds__(256) void cvt_all_kernel(CvtArgs a, int total4) {
  int i = blockIdx.x * 256 + threadIdx.x;
  if (i >= total4) return;
  int s = 0;
#pragma unroll
  for (int k = 0; k < 7; ++k) s += (i >= a.cum[k + 1]) ? 1 : 0;
  int off = i - a.cum[s];
  float4 f = ((const float4*)a.src[s])[off];
  ushort4 o;
  o.x = f2bf(f.x); o.y = f2bf(f.y); o.z = f2bf(f.z); o.w = f2bf(f.w);
  ((ushort4*)a.dst[s])[off] = o;
}

// ---------- GEMM core: BK=64, XOR-8 swizzled LDS ----------
// Tile in LDS: 128 rows x 64 bf16 (128 B/row) = 16 KB.
// Chunk = 16 B. Within a row, chunk slot cs holds logical chunk c = cs ^ (row&7).
// Staged with global_load_lds width=16: LDS byte = t*16 + k*4096 (wave-uniform
// base + lane*16); global address carries the XOR so the swizzle costs nothing.
__device__ __forceinline__ void stage_tile64(const unsigned short* __restrict__ g, int ldK,
                                             int tileRow, int k0, char* lds, int t) {
  char* l0 = lds + ((t >> 6) << 10);  // wave-uniform base
#pragma unroll
  for (int k = 0; k < 4; ++k) {
    int linear = t + k * 256;        // 16-B chunk id within tile, 0..1023
    int row = linear >> 3;           // 0..127
    int cs  = linear & 7;            // chunk slot in row
    int c   = cs ^ (row & 7);        // logical chunk -> global column
    const unsigned short* gp = g + (size_t)(tileRow + row) * ldK + (k0 + c * 8);
    __builtin_amdgcn_global_load_lds((const __attribute__((address_space(1))) void*)gp,
                                     (__attribute__((address_space(3))) void*)(l0 + k * 4096),
                                     16, 0, 0);
  }
}

// C[row, col] += A[rowBase..+128, 0..K) * W[colBase..+128, 0..K)^T
// A, W row-major with K contiguous.
__device__ __forceinline__ void gemm_seg(const unsigned short* __restrict__ A,
                                         const unsigned short* __restrict__ W,
                                         int K, int rowBase, int colBase,
                                         char* ldsA, char* ldsB,
                                         f32x4 (&acc)[4][4], int t) {
  const int lane = t & 63;
  const int wid  = t >> 6;
  const int wm   = wid >> 1, wn = wid & 1;   // wave 2x2 -> 64x64 each
  const int lrow = lane & 15;
  const int quad = lane >> 4;
  const int r7   = lrow & 7;                 // (row & 7) for all frag rows
  for (int k0 = 0; k0 < K; k0 += 64) {
    stage_tile64(A, K, rowBase, k0, ldsA, t);
    stage_tile64(W, K, colBase, k0, ldsB, t);
    __syncthreads();                         // drains vmcnt -> LDS ready
#pragma unroll
    for (int kk = 0; kk < 2; ++kk) {
      const int swz = (((kk << 2) | quad) ^ r7) * 16;
      bf16x8 af[4], bfr[4];
#pragma unroll
      for (int i = 0; i < 4; ++i) {
        int ra = wm * 64 + i * 16 + lrow;
        int rb = wn * 64 + i * 16 + lrow;
        af[i]  = *(const bf16x8*)(ldsA + ra * 128 + swz);
        bfr[i] = *(const bf16x8*)(ldsB + rb * 128 + swz);
      }
#pragma unroll
      for (int i = 0; i < 4; ++i)
#pragma unroll
        for (int j = 0; j < 4; ++j)
          acc[i][j] = __builtin_amdgcn_mfma_f32_16x16x32_bf16(af[i], bfr[j], acc[i][j], 0, 0, 0);
    }
    __syncthreads();                         // all reads done before restage
  }
}

__device__ __forceinline__ float fast_sigmoid(float v) {
  return 1.0f / (1.0f + __expf(-v));
}
__device__ __forceinline__ float fast_tanh(float v) {
  float e = __expf(2.0f * v);
  return 1.0f - 2.0f / (e + 1.0f);   // safe at +/-inf
}

// ---------- Kernel A: R and Z gates (blockIdx.z: 0 -> R, 1 -> Z) ----------
__global__ __launch_bounds__(256) void gate_rz(
    const unsigned short* __restrict__ xb, const unsigned short* __restrict__ hb,
    const unsigned short* __restrict__ Wr, const unsigned short* __restrict__ Ur,
    const unsigned short* __restrict__ Wz, const unsigned short* __restrict__ Uz,
    const float* __restrict__ br, const float* __restrict__ bz,
    const float* __restrict__ hprev,
    unsigned short* __restrict__ rh, float* __restrict__ Zbuf) {
  __shared__ char lds[32768];
  char* ldsA = lds;
  char* ldsB = lds + 16384;
  const int t = threadIdx.x;
  const int rowBase = blockIdx.y * 128;
  const int colBase = blockIdx.x * 128;
  const bool isZ = (blockIdx.z != 0);
  const unsigned short* W = isZ ? Wz : Wr;
  const unsigned short* U = isZ ? Uz : Ur;
  const float* bias = isZ ? bz : br;

  f32x4 acc[4][4];
#pragma unroll
  for (int i = 0; i < 4; ++i)
#pragma unroll
    for (int j = 0; j < 4; ++j)
      acc[i][j] = (f32x4){0.f, 0.f, 0.f, 0.f};

  gemm_seg(xb, W, ISZ, rowBase, colBase, ldsA, ldsB, acc, t);
  gemm_seg(hb, U, HSZ, rowBase, colBase, ldsA, ldsB, acc, t);

  const int lane = t & 63, wid = t >> 6;
  const int wm = wid >> 1, wn = wid & 1, lrow = lane & 15, quad = lane >> 4;
#pragma unroll
  for (int i = 0; i < 4; ++i) {
#pragma unroll
    for (int j = 0; j < 4; ++j) {
      int col = colBase + wn * 64 + j * 16 + lrow;
      float bv = bias[col];
#pragma unroll
      for (int r = 0; r < 4; ++r) {
        int row = rowBase + wm * 64 + i * 16 + quad * 4 + r;
        float s = fast_sigmoid(acc[i][j][r] + bv);
        int idx = row * HSZ + col;
        if (isZ) {
          Zbuf[idx] = s;
        } else {
          rh[idx] = f2bf(s * hprev[idx]);
        }
      }
    }
  }
}

// ---------- Kernel B: candidate h + final blend ----------
__global__ __launch_bounds__(256) void gate_h(
    const unsigned short* __restrict__ xb, const unsigned short* __restrict__ rhb,
    const unsigned short* __restrict__ Wh, const unsigned short* __restrict__ Uh,
    const float* __restrict__ bh, const float* __restrict__ Zbuf,
    const float* __restrict__ hprev, float* __restrict__ out) {
  __shared__ char lds[32768];
  char* ldsA = lds;
  char* ldsB = lds + 16384;
  const int t = threadIdx.x;
  const int rowBase = blockIdx.y * 128;
  const int colBase = blockIdx.x * 128;

  f32x4 acc[4][4];
#pragma unroll
  for (int i = 0; i < 4; ++i)
#pragma unroll
    for (int j = 0; j < 4; ++j)
      acc[i][j] = (f32x4){0.f, 0.f, 0.f, 0.f};

  gemm_seg(xb, Wh, ISZ, rowBase, colBase, ldsA, ldsB, acc, t);
  gemm_seg(rhb, Uh, HSZ, rowBase, colBase, ldsA, ldsB, acc, t);

  const int lane = t & 63, wid = t >> 6;
  const int wm = wid >> 1, wn = wid & 1, lrow = lane & 15, quad = lane >> 4;
#pragma unroll
  for (int i = 0; i < 4; ++i) {
#pragma unroll
    for (int j = 0; j < 4; ++j) {
      int col = colBase + wn * 64 + j * 16 + lrow;
      float bv = bh[col];
#pragma unroll
      for (int r = 0; r < 4; ++r) {
        int row = rowBase + wm * 64 + i * 16 + quad * 4 + r;
        float hp = fast_tanh(acc[i][j][r] + bv);
        int idx = row * HSZ + col;
        float z = Zbuf[idx];
        float h = hprev[idx];
        out[idx] = h + z * (hp - h);
      }
    }
  }
}

// ---------- host ----------
extern "C" void kernel_launch(void* const* d_in, const int* in_sizes, int n_in,
                              void* d_out, int out_size, void* d_ws, size_t ws_size,
                              hipStream_t stream) {
  (void)in_sizes; (void)n_in; (void)out_size; (void)ws_size;
  const float* x     = (const float*)d_in[0];
  const float* hprev = (const float*)d_in[1];
  const float* Wh    = (const float*)d_in[2];
  const float* Wz    = (const float*)d_in[3];
  const float* Wr    = (const float*)d_in[4];
  const float* Uh    = (const float*)d_in[5];
  const float* Uz    = (const float*)d_in[6];
  const float* Ur    = (const float*)d_in[7];
  const float* bh    = (const float*)d_in[8];
  const float* bz    = (const float*)d_in[9];
  const float* br    = (const float*)d_in[10];
  float* out = (float*)d_out;

  char* ws = (char*)d_ws;
  size_t off = 0;
  auto alloc = [&](size_t bytes) { char* p = ws + off; off += bytes; return p; };
  unsigned short* xb  = (unsigned short*)alloc((size_t)BATCH * ISZ * 2);
  unsigned short* hb  = (unsigned short*)alloc((size_t)BATCH * HSZ * 2);
  unsigned short* Wrb = (unsigned short*)alloc((size_t)HSZ * ISZ * 2);
  unsigned short* Wzb = (unsigned short*)alloc((size_t)HSZ * ISZ * 2);
  unsigned short* Whb = (unsigned short*)alloc((size_t)HSZ * ISZ * 2);
  unsigned short* Urb = (unsigned short*)alloc((size_t)HSZ * HSZ * 2);
  unsigned short* Uzb = (unsigned short*)alloc((size_t)HSZ * HSZ * 2);
  unsigned short* Uhb = (unsigned short*)alloc((size_t)HSZ * HSZ * 2);
  unsigned short* rhb = (unsigned short*)alloc((size_t)BATCH * HSZ * 2);
  float*          Zb  = (float*)alloc((size_t)BATCH * HSZ * 4);

  // one fused convert launch for all 8 tensors
  CvtArgs ca;
  const float* srcs[8]      = {x, hprev, Wr, Wz, Wh, Ur, Uz, Uh};
  unsigned short* dsts[8]   = {xb, hb, Wrb, Wzb, Whb, Urb, Uzb, Uhb};
  int n4s[8] = {BATCH * ISZ / 4, BATCH * HSZ / 4,
                HSZ * ISZ / 4, HSZ * ISZ / 4, HSZ * ISZ / 4,
                HSZ * HSZ / 4, HSZ * HSZ / 4, HSZ * HSZ / 4};
  int cum = 0;
  for (int i = 0; i < 8; ++i) {
    ca.src[i] = srcs[i];
    ca.dst[i] = dsts[i];
    ca.cum[i] = cum;
    cum += n4s[i];
  }
  ca.cum[8] = cum;
  cvt_all_kernel<<<(cum + 255) / 256, 256, 0, stream>>>(ca, cum);

  dim3 gridA(HSZ / 128, BATCH / 128, 2);
  gate_rz<<<gridA, 256, 0, stream>>>(xb, hb, Wrb, Urb, Wzb, Uzb, br, bz, hprev, rhb, Zb);

  dim3 gridB(HSZ / 128, BATCH / 128, 1);
  gate_h<<<gridB, 256, 0, stream>>>(xb, rhb, Whb, Uhb, bh, Zb, hprev, out);
}

// Round 3
// 347.252 us; speedup vs baseline: 1.2183x; 1.0934x over previous
//
#include <hip/hip_runtime.h>

#define BATCH 4096
#define ISZ   1024
#define HSZ   2048

typedef __bf16 bf16x8 __attribute__((ext_vector_type(8)));
typedef float  f32x4  __attribute__((ext_vector_type(4)));

// ---------- fp32 <-> bf16 ----------
__device__ __forceinline__ unsigned short f2bf(float f) {
  unsigned u = __builtin_bit_cast(unsigned, f);
  u += 0x7fffu + ((u >> 16) & 1u);
  return (unsigned short)(u >> 16);
}
__device__ __forceinline__ float bf2f(unsigned short s) {
  unsigned u = ((unsigned)s) << 16;
  return __builtin_bit_cast(float, u);
}

// ---------- fused convert: all 8 tensors in ONE launch ----------
struct CvtArgs {
  const float* src[8];
  unsigned short* dst[8];
  int cum[9];   // prefix sums of float4 counts
};

__global__ __launch_bounds__(256) void cvt_all_kernel(CvtArgs a, int total4) {
  int i = blockIdx.x * 256 + threadIdx.x;
  if (i >= total4) return;
  int s = 0;
#pragma unroll
  for (int k = 0; k < 7; ++k) s += (i >= a.cum[k + 1]) ? 1 : 0;
  int off = i - a.cum[s];
  float4 f = ((const float4*)a.src[s])[off];
  ushort4 o;
  o.x = f2bf(f.x); o.y = f2bf(f.y); o.z = f2bf(f.z); o.w = f2bf(f.w);
  ((ushort4*)a.dst[s])[off] = o;
}

// ---------- GEMM core: BK=64, XOR-8 swizzled LDS (conflict-free, verified R2) ----------
__device__ __forceinline__ void stage_tile64(const unsigned short* __restrict__ g, int ldK,
                                             int tileRow, int k0, char* lds, int t) {
  char* l0 = lds + ((t >> 6) << 10);  // wave-uniform base
#pragma unroll
  for (int k = 0; k < 4; ++k) {
    int linear = t + k * 256;        // 16-B chunk id within tile, 0..1023
    int row = linear >> 3;           // 0..127
    int cs  = linear & 7;            // chunk slot in row
    int c   = cs ^ (row & 7);        // logical chunk -> global column
    const unsigned short* gp = g + (size_t)(tileRow + row) * ldK + (k0 + c * 8);
    __builtin_amdgcn_global_load_lds((const __attribute__((address_space(1))) void*)gp,
                                     (__attribute__((address_space(3))) void*)(l0 + k * 4096),
                                     16, 0, 0);
  }
}

__device__ __forceinline__ void gemm_seg(const unsigned short* __restrict__ A,
                                         const unsigned short* __restrict__ W,
                                         int K, int rowBase, int colBase,
                                         char* ldsA, char* ldsB,
                                         f32x4 (&acc)[4][4], int t) {
  const int lane = t & 63;
  const int wid  = t >> 6;
  const int wm   = wid >> 1, wn = wid & 1;   // wave 2x2 -> 64x64 each
  const int lrow = lane & 15;
  const int quad = lane >> 4;
  const int r7   = lrow & 7;
  for (int k0 = 0; k0 < K; k0 += 64) {
    stage_tile64(A, K, rowBase, k0, ldsA, t);
    stage_tile64(W, K, colBase, k0, ldsB, t);
    __syncthreads();
#pragma unroll
    for (int kk = 0; kk < 2; ++kk) {
      const int swz = (((kk << 2) | quad) ^ r7) * 16;
      bf16x8 af[4], bfr[4];
#pragma unroll
      for (int i = 0; i < 4; ++i) {
        int ra = wm * 64 + i * 16 + lrow;
        int rb = wn * 64 + i * 16 + lrow;
        af[i]  = *(const bf16x8*)(ldsA + ra * 128 + swz);
        bfr[i] = *(const bf16x8*)(ldsB + rb * 128 + swz);
      }
#pragma unroll
      for (int i = 0; i < 4; ++i)
#pragma unroll
        for (int j = 0; j < 4; ++j)
          acc[i][j] = __builtin_amdgcn_mfma_f32_16x16x32_bf16(af[i], bfr[j], acc[i][j], 0, 0, 0);
    }
    __syncthreads();
  }
}

__device__ __forceinline__ float fast_sigmoid(float v) {
  return 1.0f / (1.0f + __expf(-v));
}
__device__ __forceinline__ float fast_tanh(float v) {
  float e = __expf(2.0f * v);
  return 1.0f - 2.0f / (e + 1.0f);   // safe at +/-inf
}

// ---------- Kernel A: R and Z gates ----------
__global__ __launch_bounds__(256, 4) void gate_rz(
    const unsigned short* __restrict__ xb, const unsigned short* __restrict__ hb,
    const unsigned short* __restrict__ Wr, const unsigned short* __restrict__ Ur,
    const unsigned short* __restrict__ Wz, const unsigned short* __restrict__ Uz,
    const float* __restrict__ br, const float* __restrict__ bz,
    unsigned short* __restrict__ rh, unsigned short* __restrict__ Zbuf) {
  __shared__ char lds[32768];
  char* ldsA = lds;
  char* ldsB = lds + 16384;
  const int t = threadIdx.x;

  // weight-stationary XCD swizzle: each XCD owns 2 column-panels
  int lin = blockIdx.x + (blockIdx.y << 4) + (blockIdx.z << 9);
  int xcd = lin & 7, s = lin >> 3;
  int bx = xcd * 2 + (s & 1);
  int by = (s >> 1) & 31;
  int bz_ = s >> 6;

  const int rowBase = by * 128;
  const int colBase = bx * 128;
  const bool isZ = (bz_ != 0);
  const unsigned short* W = isZ ? Wz : Wr;
  const unsigned short* U = isZ ? Uz : Ur;
  const float* biasP = isZ ? bz : br;

  f32x4 acc[4][4];
#pragma unroll
  for (int i = 0; i < 4; ++i)
#pragma unroll
    for (int j = 0; j < 4; ++j)
      acc[i][j] = (f32x4){0.f, 0.f, 0.f, 0.f};

  gemm_seg(xb, W, ISZ, rowBase, colBase, ldsA, ldsB, acc, t);
  gemm_seg(hb, U, HSZ, rowBase, colBase, ldsA, ldsB, acc, t);

  const int lane = t & 63, wid = t >> 6;
  const int wm = wid >> 1, wn = wid & 1, lrow = lane & 15, quad = lane >> 4;
#pragma unroll
  for (int i = 0; i < 4; ++i) {
#pragma unroll
    for (int j = 0; j < 4; ++j) {
      int col = colBase + wn * 64 + j * 16 + lrow;
      float bv = biasP[col];
#pragma unroll
      for (int r = 0; r < 4; ++r) {
        int row = rowBase + wm * 64 + i * 16 + quad * 4 + r;
        float sg = fast_sigmoid(acc[i][j][r] + bv);
        int idx = row * HSZ + col;
        if (isZ) {
          Zbuf[idx] = f2bf(sg);
        } else {
          rh[idx] = f2bf(sg * bf2f(hb[idx]));
        }
      }
    }
  }
}

// ---------- Kernel B: candidate h + final blend ----------
__global__ __launch_bounds__(256, 4) void gate_h(
    const unsigned short* __restrict__ xb, const unsigned short* __restrict__ rhb,
    const unsigned short* __restrict__ Wh, const unsigned short* __restrict__ Uh,
    const float* __restrict__ bh, const unsigned short* __restrict__ Zbuf,
    const float* __restrict__ hprev, float* __restrict__ out) {
  __shared__ char lds[32768];
  char* ldsA = lds;
  char* ldsB = lds + 16384;
  const int t = threadIdx.x;

  int lin = blockIdx.x + (blockIdx.y << 4);
  int xcd = lin & 7, s = lin >> 3;
  int bx = xcd * 2 + (s & 1);
  int by = s >> 1;

  const int rowBase = by * 128;
  const int colBase = bx * 128;

  f32x4 acc[4][4];
#pragma unroll
  for (int i = 0; i < 4; ++i)
#pragma unroll
    for (int j = 0; j < 4; ++j)
      acc[i][j] = (f32x4){0.f, 0.f, 0.f, 0.f};

  gemm_seg(xb, Wh, ISZ, rowBase, colBase, ldsA, ldsB, acc, t);
  gemm_seg(rhb, Uh, HSZ, rowBase, colBase, ldsA, ldsB, acc, t);

  const int lane = t & 63, wid = t >> 6;
  const int wm = wid >> 1, wn = wid & 1, lrow = lane & 15, quad = lane >> 4;
#pragma unroll
  for (int i = 0; i < 4; ++i) {
#pragma unroll
    for (int j = 0; j < 4; ++j) {
      int col = colBase + wn * 64 + j * 16 + lrow;
      float bv = bh[col];
#pragma unroll
      for (int r = 0; r < 4; ++r) {
        int row = rowBase + wm * 64 + i * 16 + quad * 4 + r;
        float hp = fast_tanh(acc[i][j][r] + bv);
        int idx = row * HSZ + col;
        float z = bf2f(Zbuf[idx]);
        float h = hprev[idx];
        out[idx] = h + z * (hp - h);
      }
    }
  }
}

// ---------- host ----------
extern "C" void kernel_launch(void* const* d_in, const int* in_sizes, int n_in,
                              void* d_out, int out_size, void* d_ws, size_t ws_size,
                              hipStream_t stream) {
  (void)in_sizes; (void)n_in; (void)out_size; (void)ws_size;
  const float* x     = (const float*)d_in[0];
  const float* hprev = (const float*)d_in[1];
  const float* Wh    = (const float*)d_in[2];
  const float* Wz    = (const float*)d_in[3];
  const float* Wr    = (const float*)d_in[4];
  const float* Uh    = (const float*)d_in[5];
  const float* Uz    = (const float*)d_in[6];
  const float* Ur    = (const float*)d_in[7];
  const float* bh    = (const float*)d_in[8];
  const float* bz    = (const float*)d_in[9];
  const float* br    = (const float*)d_in[10];
  float* out = (float*)d_out;

  char* ws = (char*)d_ws;
  size_t off = 0;
  auto alloc = [&](size_t bytes) { char* p = ws + off; off += bytes; return p; };
  unsigned short* xb  = (unsigned short*)alloc((size_t)BATCH * ISZ * 2);
  unsigned short* hb  = (unsigned short*)alloc((size_t)BATCH * HSZ * 2);
  unsigned short* Wrb = (unsigned short*)alloc((size_t)HSZ * ISZ * 2);
  unsigned short* Wzb = (unsigned short*)alloc((size_t)HSZ * ISZ * 2);
  unsigned short* Whb = (unsigned short*)alloc((size_t)HSZ * ISZ * 2);
  unsigned short* Urb = (unsigned short*)alloc((size_t)HSZ * HSZ * 2);
  unsigned short* Uzb = (unsigned short*)alloc((size_t)HSZ * HSZ * 2);
  unsigned short* Uhb = (unsigned short*)alloc((size_t)HSZ * HSZ * 2);
  unsigned short* rhb = (unsigned short*)alloc((size_t)BATCH * HSZ * 2);
  unsigned short* Zb  = (unsigned short*)alloc((size_t)BATCH * HSZ * 2);

  CvtArgs ca;
  const float* srcs[8]      = {x, hprev, Wr, Wz, Wh, Ur, Uz, Uh};
  unsigned short* dsts[8]   = {xb, hb, Wrb, Wzb, Whb, Urb, Uzb, Uhb};
  int n4s[8] = {BATCH * ISZ / 4, BATCH * HSZ / 4,
                HSZ * ISZ / 4, HSZ * ISZ / 4, HSZ * ISZ / 4,
                HSZ * HSZ / 4, HSZ * HSZ / 4, HSZ * HSZ / 4};
  int cum = 0;
  for (int i = 0; i < 8; ++i) {
    ca.src[i] = srcs[i];
    ca.dst[i] = dsts[i];
    ca.cum[i] = cum;
    cum += n4s[i];
  }
  ca.cum[8] = cum;
  cvt_all_kernel<<<(cum + 255) / 256, 256, 0, stream>>>(ca, cum);

  dim3 gridA(HSZ / 128, BATCH / 128, 2);
  gate_rz<<<gridA, 256, 0, stream>>>(xb, hb, Wrb, Urb, Wzb, Uzb, br, bz, rhb, Zb);

  dim3 gridB(HSZ / 128, BATCH / 128, 1);
  gate_h<<<gridB, 256, 0, stream>>>(xb, rhb, Whb, Uhb, bh, Zb, hprev, out);
}

// Round 4
// 343.209 us; speedup vs baseline: 1.2326x; 1.0118x over previous
//
#include <hip/hip_runtime.h>

#define BATCH 4096
#define ISZ   1024
#define HSZ   2048

typedef __bf16 bf16x8 __attribute__((ext_vector_type(8)));
typedef float  f32x4  __attribute__((ext_vector_type(4)));

// ---------- fp32 <-> bf16 ----------
__device__ __forceinline__ unsigned short f2bf(float f) {
  unsigned u = __builtin_bit_cast(unsigned, f);
  u += 0x7fffu + ((u >> 16) & 1u);
  return (unsigned short)(u >> 16);
}
__device__ __forceinline__ float bf2f(unsigned short s) {
  unsigned u = ((unsigned)s) << 16;
  return __builtin_bit_cast(float, u);
}

// ---------- fused convert: all 8 tensors in ONE launch ----------
struct CvtArgs {
  const float* src[8];
  unsigned short* dst[8];
  int cum[9];   // prefix sums of float4 counts
};

__global__ __launch_bounds__(256) void cvt_all_kernel(CvtArgs a, int total4) {
  int i = blockIdx.x * 256 + threadIdx.x;
  if (i >= total4) return;
  int s = 0;
#pragma unroll
  for (int k = 0; k < 7; ++k) s += (i >= a.cum[k + 1]) ? 1 : 0;
  int off = i - a.cum[s];
  float4 f = ((const float4*)a.src[s])[off];
  ushort4 o;
  o.x = f2bf(f.x); o.y = f2bf(f.y); o.z = f2bf(f.z); o.w = f2bf(f.w);
  ((ushort4*)a.dst[s])[off] = o;
}

// ---------- staging: BK=64, XOR-8 swizzled LDS (conflict-free, verified R2) ----------
// 128-row A tile: 1024 16-B chunks, 4 per thread.
__device__ __forceinline__ void stage_tile64(const unsigned short* __restrict__ g, int ldK,
                                             int tileRow, int k0, char* lds, int t) {
  char* l0 = lds + ((t >> 6) << 10);  // wave-uniform base
#pragma unroll
  for (int k = 0; k < 4; ++k) {
    int linear = t + k * 256;        // chunk id, 0..1023
    int row = linear >> 3;           // 0..127
    int cs  = linear & 7;
    int c   = cs ^ (row & 7);        // XOR swizzle on global side
    const unsigned short* gp = g + (size_t)(tileRow + row) * ldK + (k0 + c * 8);
    __builtin_amdgcn_global_load_lds((const __attribute__((address_space(1))) void*)gp,
                                     (__attribute__((address_space(3))) void*)(l0 + k * 4096),
                                     16, 0, 0);
  }
}

// 64-row B tile (gate_h): 512 chunks, 2 per thread.
__device__ __forceinline__ void stage_tileB64(const unsigned short* __restrict__ g, int ldK,
                                              int tileRow, int k0, char* lds, int t) {
  char* l0 = lds + ((t >> 6) << 10);
#pragma unroll
  for (int k = 0; k < 2; ++k) {
    int linear = t + k * 256;        // chunk id, 0..511
    int row = linear >> 3;           // 0..63
    int cs  = linear & 7;
    int c   = cs ^ (row & 7);
    const unsigned short* gp = g + (size_t)(tileRow + row) * ldK + (k0 + c * 8);
    __builtin_amdgcn_global_load_lds((const __attribute__((address_space(1))) void*)gp,
                                     (__attribute__((address_space(3))) void*)(l0 + k * 4096),
                                     16, 0, 0);
  }
}

// ---------- 128x128 GEMM segment (gate_rz; verified R3, 937 TF) ----------
__device__ __forceinline__ void gemm_seg(const unsigned short* __restrict__ A,
                                         const unsigned short* __restrict__ W,
                                         int K, int rowBase, int colBase,
                                         char* ldsA, char* ldsB,
                                         f32x4 (&acc)[4][4], int t) {
  const int lane = t & 63;
  const int wid  = t >> 6;
  const int wm   = wid >> 1, wn = wid & 1;
  const int lrow = lane & 15;
  const int quad = lane >> 4;
  const int r7   = lrow & 7;
  for (int k0 = 0; k0 < K; k0 += 64) {
    stage_tile64(A, K, rowBase, k0, ldsA, t);
    stage_tile64(W, K, colBase, k0, ldsB, t);
    __syncthreads();
#pragma unroll
    for (int kk = 0; kk < 2; ++kk) {
      const int swz = (((kk << 2) | quad) ^ r7) * 16;
      bf16x8 af[4], bfr[4];
#pragma unroll
      for (int i = 0; i < 4; ++i) {
        af[i]  = *(const bf16x8*)(ldsA + (wm * 64 + i * 16 + lrow) * 128 + swz);
        bfr[i] = *(const bf16x8*)(ldsB + (wn * 64 + i * 16 + lrow) * 128 + swz);
      }
#pragma unroll
      for (int i = 0; i < 4; ++i)
#pragma unroll
        for (int j = 0; j < 4; ++j)
          acc[i][j] = __builtin_amdgcn_mfma_f32_16x16x32_bf16(af[i], bfr[j], acc[i][j], 0, 0, 0);
    }
    __syncthreads();
  }
}

// ---------- 128x64 GEMM segment (gate_h; wave tile 64x32, acc = 32 regs) ----------
__device__ __forceinline__ void gemm_seg_h(const unsigned short* __restrict__ A,
                                           const unsigned short* __restrict__ W,
                                           int K, int rowBase, int colBase,
                                           char* ldsA, char* ldsB,
                                           f32x4 (&acc)[4][2], int t) {
  const int lane = t & 63;
  const int wid  = t >> 6;
  const int wm   = wid >> 1, wn = wid & 1;
  const int lrow = lane & 15;
  const int quad = lane >> 4;
  const int r7   = lrow & 7;
  for (int k0 = 0; k0 < K; k0 += 64) {
    stage_tile64(A, K, rowBase, k0, ldsA, t);
    stage_tileB64(W, K, colBase, k0, ldsB, t);
    __syncthreads();
#pragma unroll
    for (int kk = 0; kk < 2; ++kk) {
      const int swz = (((kk << 2) | quad) ^ r7) * 16;
      bf16x8 af[4], bfr[2];
#pragma unroll
      for (int i = 0; i < 4; ++i)
        af[i]  = *(const bf16x8*)(ldsA + (wm * 64 + i * 16 + lrow) * 128 + swz);
#pragma unroll
      for (int j = 0; j < 2; ++j)
        bfr[j] = *(const bf16x8*)(ldsB + (wn * 32 + j * 16 + lrow) * 128 + swz);
#pragma unroll
      for (int i = 0; i < 4; ++i)
#pragma unroll
        for (int j = 0; j < 2; ++j)
          acc[i][j] = __builtin_amdgcn_mfma_f32_16x16x32_bf16(af[i], bfr[j], acc[i][j], 0, 0, 0);
    }
    __syncthreads();
  }
}

__device__ __forceinline__ float fast_sigmoid(float v) {
  return 1.0f / (1.0f + __expf(-v));
}
__device__ __forceinline__ float fast_tanh(float v) {
  float e = __expf(2.0f * v);
  return 1.0f - 2.0f / (e + 1.0f);   // safe at +/-inf
}

// ---------- Kernel A: R and Z gates (unchanged from R3: 937 TF) ----------
__global__ __launch_bounds__(256, 4) void gate_rz(
    const unsigned short* __restrict__ xb, const unsigned short* __restrict__ hb,
    const unsigned short* __restrict__ Wr, const unsigned short* __restrict__ Ur,
    const unsigned short* __restrict__ Wz, const unsigned short* __restrict__ Uz,
    const float* __restrict__ br, const float* __restrict__ bz,
    unsigned short* __restrict__ rh, unsigned short* __restrict__ Zbuf) {
  __shared__ char lds[32768];
  char* ldsA = lds;
  char* ldsB = lds + 16384;
  const int t = threadIdx.x;

  // weight-stationary XCD swizzle: each XCD owns 2 column-panels
  int lin = blockIdx.x + (blockIdx.y << 4) + (blockIdx.z << 9);
  int xcd = lin & 7, s = lin >> 3;
  int bx = xcd * 2 + (s & 1);
  int by = (s >> 1) & 31;
  int bz_ = s >> 6;

  const int rowBase = by * 128;
  const int colBase = bx * 128;
  const bool isZ = (bz_ != 0);
  const unsigned short* W = isZ ? Wz : Wr;
  const unsigned short* U = isZ ? Uz : Ur;
  const float* biasP = isZ ? bz : br;

  f32x4 acc[4][4];
#pragma unroll
  for (int i = 0; i < 4; ++i)
#pragma unroll
    for (int j = 0; j < 4; ++j)
      acc[i][j] = (f32x4){0.f, 0.f, 0.f, 0.f};

  gemm_seg(xb, W, ISZ, rowBase, colBase, ldsA, ldsB, acc, t);
  gemm_seg(hb, U, HSZ, rowBase, colBase, ldsA, ldsB, acc, t);

  const int lane = t & 63, wid = t >> 6;
  const int wm = wid >> 1, wn = wid & 1, lrow = lane & 15, quad = lane >> 4;
#pragma unroll
  for (int i = 0; i < 4; ++i) {
#pragma unroll
    for (int j = 0; j < 4; ++j) {
      int col = colBase + wn * 64 + j * 16 + lrow;
      float bv = biasP[col];
#pragma unroll
      for (int r = 0; r < 4; ++r) {
        int row = rowBase + wm * 64 + i * 16 + quad * 4 + r;
        float sg = fast_sigmoid(acc[i][j][r] + bv);
        int idx = row * HSZ + col;
        if (isZ) {
          Zbuf[idx] = f2bf(sg);
        } else {
          rh[idx] = f2bf(sg * bf2f(hb[idx]));
        }
      }
    }
  }
}

// ---------- Kernel B: candidate h + blend. 128x64 tiles -> 1024 blocks, 5/CU ----------
__global__ __launch_bounds__(256, 5) void gate_h(
    const unsigned short* __restrict__ xb, const unsigned short* __restrict__ rhb,
    const unsigned short* __restrict__ Wh, const unsigned short* __restrict__ Uh,
    const float* __restrict__ bh, const unsigned short* __restrict__ Zbuf,
    const float* __restrict__ hprev, float* __restrict__ out) {
  __shared__ char lds[24576];
  char* ldsA = lds;
  char* ldsB = lds + 16384;
  const int t = threadIdx.x;

  // weight-stationary XCD swizzle: each XCD owns 4 column-panels of 64
  int lin = blockIdx.x + (blockIdx.y << 5);   // grid (32, 32)
  int xcd = lin & 7, s = lin >> 3;            // s in [0,128)
  int bx = xcd * 4 + (s & 3);                 // 32 col-panels
  int by = s >> 2;                            // 32 row-panels

  const int rowBase = by * 128;
  const int colBase = bx * 64;

  f32x4 acc[4][2];
#pragma unroll
  for (int i = 0; i < 4; ++i)
#pragma unroll
    for (int j = 0; j < 2; ++j)
      acc[i][j] = (f32x4){0.f, 0.f, 0.f, 0.f};

  gemm_seg_h(xb, Wh, ISZ, rowBase, colBase, ldsA, ldsB, acc, t);
  gemm_seg_h(rhb, Uh, HSZ, rowBase, colBase, ldsA, ldsB, acc, t);

  const int lane = t & 63, wid = t >> 6;
  const int wm = wid >> 1, wn = wid & 1, lrow = lane & 15, quad = lane >> 4;
#pragma unroll
  for (int i = 0; i < 4; ++i) {
#pragma unroll
    for (int j = 0; j < 2; ++j) {
      int col = colBase + wn * 32 + j * 16 + lrow;
      float bv = bh[col];
#pragma unroll
      for (int r = 0; r < 4; ++r) {
        int row = rowBase + wm * 64 + i * 16 + quad * 4 + r;
        float hp = fast_tanh(acc[i][j][r] + bv);
        int idx = row * HSZ + col;
        float z = bf2f(Zbuf[idx]);
        float h = hprev[idx];
        out[idx] = h + z * (hp - h);
      }
    }
  }
}

// ---------- host ----------
extern "C" void kernel_launch(void* const* d_in, const int* in_sizes, int n_in,
                              void* d_out, int out_size, void* d_ws, size_t ws_size,
                              hipStream_t stream) {
  (void)in_sizes; (void)n_in; (void)out_size; (void)ws_size;
  const float* x     = (const float*)d_in[0];
  const float* hprev = (const float*)d_in[1];
  const float* Wh    = (const float*)d_in[2];
  const float* Wz    = (const float*)d_in[3];
  const float* Wr    = (const float*)d_in[4];
  const float* Uh    = (const float*)d_in[5];
  const float* Uz    = (const float*)d_in[6];
  const float* Ur    = (const float*)d_in[7];
  const float* bh    = (const float*)d_in[8];
  const float* bz    = (const float*)d_in[9];
  const float* br    = (const float*)d_in[10];
  float* out = (float*)d_out;

  char* ws = (char*)d_ws;
  size_t off = 0;
  auto alloc = [&](size_t bytes) { char* p = ws + off; off += bytes; return p; };
  unsigned short* xb  = (unsigned short*)alloc((size_t)BATCH * ISZ * 2);
  unsigned short* hb  = (unsigned short*)alloc((size_t)BATCH * HSZ * 2);
  unsigned short* Wrb = (unsigned short*)alloc((size_t)HSZ * ISZ * 2);
  unsigned short* Wzb = (unsigned short*)alloc((size_t)HSZ * ISZ * 2);
  unsigned short* Whb = (unsigned short*)alloc((size_t)HSZ * ISZ * 2);
  unsigned short* Urb = (unsigned short*)alloc((size_t)HSZ * HSZ * 2);
  unsigned short* Uzb = (unsigned short*)alloc((size_t)HSZ * HSZ * 2);
  unsigned short* Uhb = (unsigned short*)alloc((size_t)HSZ * HSZ * 2);
  unsigned short* rhb = (unsigned short*)alloc((size_t)BATCH * HSZ * 2);
  unsigned short* Zb  = (unsigned short*)alloc((size_t)BATCH * HSZ * 2);

  CvtArgs ca;
  const float* srcs[8]      = {x, hprev, Wr, Wz, Wh, Ur, Uz, Uh};
  unsigned short* dsts[8]   = {xb, hb, Wrb, Wzb, Whb, Urb, Uzb, Uhb};
  int n4s[8] = {BATCH * ISZ / 4, BATCH * HSZ / 4,
                HSZ * ISZ / 4, HSZ * ISZ / 4, HSZ * ISZ / 4,
                HSZ * HSZ / 4, HSZ * HSZ / 4, HSZ * HSZ / 4};
  int cum = 0;
  for (int i = 0; i < 8; ++i) {
    ca.src[i] = srcs[i];
    ca.dst[i] = dsts[i];
    ca.cum[i] = cum;
    cum += n4s[i];
  }
  ca.cum[8] = cum;
  cvt_all_kernel<<<(cum + 255) / 256, 256, 0, stream>>>(ca, cum);

  dim3 gridA(HSZ / 128, BATCH / 128, 2);
  gate_rz<<<gridA, 256, 0, stream>>>(xb, hb, Wrb, Urb, Wzb, Uzb, br, bz, rhb, Zb);

  dim3 gridB(HSZ / 64, BATCH / 128, 1);
  gate_h<<<gridB, 256, 0, stream>>>(xb, rhb, Whb, Uhb, bh, Zb, hprev, out);
}

// Round 5
// 340.283 us; speedup vs baseline: 1.2432x; 1.0086x over previous
//
#include <hip/hip_runtime.h>

#define BATCH 4096
#define ISZ   1024
#define HSZ   2048

typedef __bf16 bf16x8 __attribute__((ext_vector_type(8)));
typedef float  f32x4  __attribute__((ext_vector_type(4)));

// ---------- fp32 <-> bf16 ----------
__device__ __forceinline__ unsigned short f2bf(float f) {
  unsigned u = __builtin_bit_cast(unsigned, f);
  u += 0x7fffu + ((u >> 16) & 1u);
  return (unsigned short)(u >> 16);
}
__device__ __forceinline__ float bf2f(unsigned short s) {
  unsigned u = ((unsigned)s) << 16;
  return __builtin_bit_cast(float, u);
}

// ---------- cvt1: the 6 tensors gate_rz depends on ----------
struct CvtArgs {
  const float* src[6];
  unsigned short* dst[6];
  int cum[7];   // prefix sums of float4 counts
};

__global__ __launch_bounds__(256) void cvt_all_kernel(CvtArgs a, int total4) {
  int i = blockIdx.x * 256 + threadIdx.x;
  if (i >= total4) return;
  int s = 0;
#pragma unroll
  for (int k = 0; k < 5; ++k) s += (i >= a.cum[k + 1]) ? 1 : 0;
  int off = i - a.cum[s];
  float4 f = ((const float4*)a.src[s])[off];
  ushort4 o;
  o.x = f2bf(f.x); o.y = f2bf(f.y); o.z = f2bf(f.z); o.w = f2bf(f.w);
  ((ushort4*)a.dst[s])[off] = o;
}

// ---------- staging: BK=64, XOR-8 swizzled LDS (conflict-free, verified R2) ----------
// 128-row tile, 256-thread block: 1024 16-B chunks, 4/thread.
__device__ __forceinline__ void stage_tile64(const unsigned short* __restrict__ g, int ldK,
                                             int tileRow, int k0, char* lds, int t) {
  char* l0 = lds + ((t >> 6) << 10);  // wave-uniform base
#pragma unroll
  for (int k = 0; k < 4; ++k) {
    int linear = t + k * 256;        // chunk id, 0..1023
    int row = linear >> 3;           // 0..127
    int cs  = linear & 7;
    int c   = cs ^ (row & 7);        // XOR swizzle on global side
    const unsigned short* gp = g + (size_t)(tileRow + row) * ldK + (k0 + c * 8);
    __builtin_amdgcn_global_load_lds((const __attribute__((address_space(1))) void*)gp,
                                     (__attribute__((address_space(3))) void*)(l0 + k * 4096),
                                     16, 0, 0);
  }
}

// 128-row tile, 512-thread block: 1024 chunks, 2/thread.
__device__ __forceinline__ void stage_tile64_w8(const unsigned short* __restrict__ g, int ldK,
                                                int tileRow, int k0, char* lds, int t) {
  char* l0 = lds + ((t >> 6) << 10);  // wave-uniform base (wid*1024)
#pragma unroll
  for (int k = 0; k < 2; ++k) {
    int linear = t + k * 512;        // chunk id, 0..1023
    int row = linear >> 3;
    int cs  = linear & 7;
    int c   = cs ^ (row & 7);
    const unsigned short* gp = g + (size_t)(tileRow + row) * ldK + (k0 + c * 8);
    __builtin_amdgcn_global_load_lds((const __attribute__((address_space(1))) void*)gp,
                                     (__attribute__((address_space(3))) void*)(l0 + k * 8192),
                                     16, 0, 0);
  }
}

// ---------- 128x128 GEMM segment, 4 waves (gate_rz; verified R3, 937 TF) ----------
__device__ __forceinline__ void gemm_seg(const unsigned short* __restrict__ A,
                                         const unsigned short* __restrict__ W,
                                         int K, int rowBase, int colBase,
                                         char* ldsA, char* ldsB,
                                         f32x4 (&acc)[4][4], int t) {
  const int lane = t & 63;
  const int wid  = t >> 6;
  const int wm   = wid >> 1, wn = wid & 1;
  const int lrow = lane & 15;
  const int quad = lane >> 4;
  const int r7   = lrow & 7;
  for (int k0 = 0; k0 < K; k0 += 64) {
    stage_tile64(A, K, rowBase, k0, ldsA, t);
    stage_tile64(W, K, colBase, k0, ldsB, t);
    __syncthreads();
#pragma unroll
    for (int kk = 0; kk < 2; ++kk) {
      const int swz = (((kk << 2) | quad) ^ r7) * 16;
      bf16x8 af[4], bfr[4];
#pragma unroll
      for (int i = 0; i < 4; ++i) {
        af[i]  = *(const bf16x8*)(ldsA + (wm * 64 + i * 16 + lrow) * 128 + swz);
        bfr[i] = *(const bf16x8*)(ldsB + (wn * 64 + i * 16 + lrow) * 128 + swz);
      }
#pragma unroll
      for (int i = 0; i < 4; ++i)
#pragma unroll
        for (int j = 0; j < 4; ++j)
          acc[i][j] = __builtin_amdgcn_mfma_f32_16x16x32_bf16(af[i], bfr[j], acc[i][j], 0, 0, 0);
    }
    __syncthreads();
  }
}

// ---------- 128x128 GEMM segment, 8 waves (gate_h; wave tile 64x32) ----------
__device__ __forceinline__ void gemm_seg8(const unsigned short* __restrict__ A,
                                          const unsigned short* __restrict__ W,
                                          int K, int rowBase, int colBase,
                                          char* ldsA, char* ldsB,
                                          f32x4 (&acc)[4][2], int t) {
  const int lane = t & 63;
  const int wid  = t >> 6;          // 0..7
  const int wm   = wid >> 2;        // 0..1  (row half)
  const int wn   = wid & 3;         // 0..3  (col quarter)
  const int lrow = lane & 15;
  const int quad = lane >> 4;
  const int r7   = lrow & 7;
  for (int k0 = 0; k0 < K; k0 += 64) {
    stage_tile64_w8(A, K, rowBase, k0, ldsA, t);
    stage_tile64_w8(W, K, colBase, k0, ldsB, t);
    __syncthreads();
#pragma unroll
    for (int kk = 0; kk < 2; ++kk) {
      const int swz = (((kk << 2) | quad) ^ r7) * 16;
      bf16x8 af[4], bfr[2];
#pragma unroll
      for (int i = 0; i < 4; ++i)
        af[i]  = *(const bf16x8*)(ldsA + (wm * 64 + i * 16 + lrow) * 128 + swz);
#pragma unroll
      for (int j = 0; j < 2; ++j)
        bfr[j] = *(const bf16x8*)(ldsB + (wn * 32 + j * 16 + lrow) * 128 + swz);
#pragma unroll
      for (int i = 0; i < 4; ++i)
#pragma unroll
        for (int j = 0; j < 2; ++j)
          acc[i][j] = __builtin_amdgcn_mfma_f32_16x16x32_bf16(af[i], bfr[j], acc[i][j], 0, 0, 0);
    }
    __syncthreads();
  }
}

__device__ __forceinline__ float fast_sigmoid(float v) {
  return 1.0f / (1.0f + __expf(-v));
}
__device__ __forceinline__ float fast_tanh(float v) {
  float e = __expf(2.0f * v);
  return 1.0f - 2.0f / (e + 1.0f);   // safe at +/-inf
}

// ---------- Kernel A: z==0 plane converts Wh/Uh (overlapped); z==1,2 are R,Z ----------
__global__ __launch_bounds__(256, 4) void gate_rz(
    const unsigned short* __restrict__ xb, const unsigned short* __restrict__ hb,
    const unsigned short* __restrict__ Wr, const unsigned short* __restrict__ Ur,
    const unsigned short* __restrict__ Wz, const unsigned short* __restrict__ Uz,
    const float* __restrict__ br, const float* __restrict__ bz,
    const float* __restrict__ Wh32, const float* __restrict__ Uh32,
    unsigned short* __restrict__ Whb, unsigned short* __restrict__ Uhb,
    unsigned short* __restrict__ rh, unsigned short* __restrict__ Zbuf) {
  __shared__ char lds[32768];
  const int t = threadIdx.x;

  if (blockIdx.z == 0) {
    // dispatched first (z-major last): converts Wh+Uh during gate_rz's first wave
    const int NW = (HSZ * ISZ) / 4;          // 524288 float4 in Wh
    const int NU = (HSZ * HSZ) / 4;          // 1048576 float4 in Uh
    int tid = (blockIdx.x + (blockIdx.y << 4)) * 256 + t;   // 0..131071
    for (int i = tid; i < NW + NU; i += 512 * 256) {
      const float4* s4 = (i < NW) ? (const float4*)Wh32 + i
                                  : (const float4*)Uh32 + (i - NW);
      ushort4* d4 = (i < NW) ? (ushort4*)Whb + i
                             : (ushort4*)Uhb + (i - NW);
      float4 f = *s4;
      ushort4 o;
      o.x = f2bf(f.x); o.y = f2bf(f.y); o.z = f2bf(f.z); o.w = f2bf(f.w);
      *d4 = o;
    }
    return;
  }

  char* ldsA = lds;
  char* ldsB = lds + 16384;
  // weight-stationary XCD swizzle over the 1024 gemm blocks
  int lin = blockIdx.x + (blockIdx.y << 4) + ((blockIdx.z - 1) << 9);
  int xcd = lin & 7, s = lin >> 3;
  int bx = xcd * 2 + (s & 1);
  int by = (s >> 1) & 31;
  int bz_ = s >> 6;

  const int rowBase = by * 128;
  const int colBase = bx * 128;
  const bool isZ = (bz_ != 0);
  const unsigned short* W = isZ ? Wz : Wr;
  const unsigned short* U = isZ ? Uz : Ur;
  const float* biasP = isZ ? bz : br;

  f32x4 acc[4][4];
#pragma unroll
  for (int i = 0; i < 4; ++i)
#pragma unroll
    for (int j = 0; j < 4; ++j)
      acc[i][j] = (f32x4){0.f, 0.f, 0.f, 0.f};

  gemm_seg(xb, W, ISZ, rowBase, colBase, ldsA, ldsB, acc, t);
  gemm_seg(hb, U, HSZ, rowBase, colBase, ldsA, ldsB, acc, t);

  const int lane = t & 63, wid = t >> 6;
  const int wm = wid >> 1, wn = wid & 1, lrow = lane & 15, quad = lane >> 4;
#pragma unroll
  for (int i = 0; i < 4; ++i) {
#pragma unroll
    for (int j = 0; j < 4; ++j) {
      int col = colBase + wn * 64 + j * 16 + lrow;
      float bv = biasP[col];
#pragma unroll
      for (int r = 0; r < 4; ++r) {
        int row = rowBase + wm * 64 + i * 16 + quad * 4 + r;
        float sg = fast_sigmoid(acc[i][j][r] + bv);
        int idx = row * HSZ + col;
        if (isZ) {
          Zbuf[idx] = f2bf(sg);
        } else {
          rh[idx] = f2bf(sg * bf2f(hb[idx]));
        }
      }
    }
  }
}

// ---------- Kernel B: 128x128 tile, 512 threads (8 waves), 16 waves/CU ----------
__global__ __launch_bounds__(512, 4) void gate_h(
    const unsigned short* __restrict__ xb, const unsigned short* __restrict__ rhb,
    const unsigned short* __restrict__ Wh, const unsigned short* __restrict__ Uh,
    const float* __restrict__ bh, const unsigned short* __restrict__ Zbuf,
    const float* __restrict__ hprev, float* __restrict__ out) {
  __shared__ char lds[32768];
  char* ldsA = lds;
  char* ldsB = lds + 16384;
  const int t = threadIdx.x;

  // weight-stationary XCD swizzle: each XCD owns 2 column-panels (grid 16x32)
  int lin = blockIdx.x + (blockIdx.y << 4);
  int xcd = lin & 7, s = lin >> 3;
  int bx = xcd * 2 + (s & 1);
  int by = s >> 1;

  const int rowBase = by * 128;
  const int colBase = bx * 128;

  f32x4 acc[4][2];
#pragma unroll
  for (int i = 0; i < 4; ++i)
#pragma unroll
    for (int j = 0; j < 2; ++j)
      acc[i][j] = (f32x4){0.f, 0.f, 0.f, 0.f};

  gemm_seg8(xb, Wh, ISZ, rowBase, colBase, ldsA, ldsB, acc, t);
  gemm_seg8(rhb, Uh, HSZ, rowBase, colBase, ldsA, ldsB, acc, t);

  const int lane = t & 63, wid = t >> 6;
  const int wm = wid >> 2, wn = wid & 3, lrow = lane & 15, quad = lane >> 4;
#pragma unroll
  for (int i = 0; i < 4; ++i) {
#pragma unroll
    for (int j = 0; j < 2; ++j) {
      int col = colBase + wn * 32 + j * 16 + lrow;
      float bv = bh[col];
#pragma unroll
      for (int r = 0; r < 4; ++r) {
        int row = rowBase + wm * 64 + i * 16 + quad * 4 + r;
        float hp = fast_tanh(acc[i][j][r] + bv);
        int idx = row * HSZ + col;
        float z = bf2f(Zbuf[idx]);
        float h = hprev[idx];
        out[idx] = h + z * (hp - h);
      }
    }
  }
}

// ---------- host ----------
extern "C" void kernel_launch(void* const* d_in, const int* in_sizes, int n_in,
                              void* d_out, int out_size, void* d_ws, size_t ws_size,
                              hipStream_t stream) {
  (void)in_sizes; (void)n_in; (void)out_size; (void)ws_size;
  const float* x     = (const float*)d_in[0];
  const float* hprev = (const float*)d_in[1];
  const float* Wh    = (const float*)d_in[2];
  const float* Wz    = (const float*)d_in[3];
  const float* Wr    = (const float*)d_in[4];
  const float* Uh    = (const float*)d_in[5];
  const float* Uz    = (const float*)d_in[6];
  const float* Ur    = (const float*)d_in[7];
  const float* bh    = (const float*)d_in[8];
  const float* bz    = (const float*)d_in[9];
  const float* br    = (const float*)d_in[10];
  float* out = (float*)d_out;

  char* ws = (char*)d_ws;
  size_t off = 0;
  auto alloc = [&](size_t bytes) { char* p = ws + off; off += bytes; return p; };
  unsigned short* xb  = (unsigned short*)alloc((size_t)BATCH * ISZ * 2);
  unsigned short* hb  = (unsigned short*)alloc((size_t)BATCH * HSZ * 2);
  unsigned short* Wrb = (unsigned short*)alloc((size_t)HSZ * ISZ * 2);
  unsigned short* Wzb = (unsigned short*)alloc((size_t)HSZ * ISZ * 2);
  unsigned short* Whb = (unsigned short*)alloc((size_t)HSZ * ISZ * 2);
  unsigned short* Urb = (unsigned short*)alloc((size_t)HSZ * HSZ * 2);
  unsigned short* Uzb = (unsigned short*)alloc((size_t)HSZ * HSZ * 2);
  unsigned short* Uhb = (unsigned short*)alloc((size_t)HSZ * HSZ * 2);
  unsigned short* rhb = (unsigned short*)alloc((size_t)BATCH * HSZ * 2);
  unsigned short* Zb  = (unsigned short*)alloc((size_t)BATCH * HSZ * 2);

  // cvt1: only what gate_rz needs (Wh/Uh are converted inside gate_rz's z==0 plane)
  CvtArgs ca;
  const float* srcs[6]      = {x, hprev, Wr, Wz, Ur, Uz};
  unsigned short* dsts[6]   = {xb, hb, Wrb, Wzb, Urb, Uzb};
  int n4s[6] = {BATCH * ISZ / 4, BATCH * HSZ / 4,
                HSZ * ISZ / 4, HSZ * ISZ / 4,
                HSZ * HSZ / 4, HSZ * HSZ / 4};
  int cum = 0;
  for (int i = 0; i < 6; ++i) {
    ca.src[i] = srcs[i];
    ca.dst[i] = dsts[i];
    ca.cum[i] = cum;
    cum += n4s[i];
  }
  ca.cum[6] = cum;
  cvt_all_kernel<<<(cum + 255) / 256, 256, 0, stream>>>(ca, cum);

  dim3 gridA(HSZ / 128, BATCH / 128, 3);   // z=0: Wh/Uh cvt plane; z=1,2: R,Z gemm
  gate_rz<<<gridA, 256, 0, stream>>>(xb, hb, Wrb, Urb, Wzb, Uzb, br, bz,
                                     Wh, Uh, Whb, Uhb, rhb, Zb);

  dim3 gridB(HSZ / 128, BATCH / 128, 1);
  gate_h<<<gridB, 512, 0, stream>>>(xb, rhb, Whb, Uhb, bh, Zb, hprev, out);
}